// Round 4
// baseline (666.413 us; speedup 1.0000x reference)
//
#include <hip/hip_runtime.h>
#include <hip/hip_bf16.h>
#include <cstdint>

typedef __bf16 bf16x8 __attribute__((ext_vector_type(8)));
typedef float f32x4 __attribute__((ext_vector_type(4)));
typedef float f32x16 __attribute__((ext_vector_type(16)));

#define MFMA16(a, b, c) __builtin_amdgcn_mfma_f32_16x16x32_bf16(a, b, c, 0, 0, 0)
#define MFMA32(a, b, c) __builtin_amdgcn_mfma_f32_32x32x16_bf16(a, b, c, 0, 0, 0)

__device__ __forceinline__ void gload_lds16(const void* g, void* l) {
  __builtin_amdgcn_global_load_lds(
      (const __attribute__((address_space(1))) unsigned int*)g,
      (__attribute__((address_space(3))) unsigned int*)l, 16, 0, 0);
}

__device__ __forceinline__ unsigned short f2bf(float x) {
  union { float f; uint32_t u; } v; v.f = x;
  uint32_t r = v.u + 0x7fff + ((v.u >> 16) & 1);
  return (unsigned short)(r >> 16);
}
__device__ __forceinline__ float bf2f(unsigned short h) {
  union { float f; uint32_t u; } v; v.u = ((uint32_t)h) << 16;
  return v.f;
}
__device__ __forceinline__ f32x16 fzero16() {
  f32x16 v;
#pragma unroll
  for (int i = 0; i < 16; ++i) v[i] = 0.f;
  return v;
}

// S-tile (f32x16, pre-scaled by sc*log2e via Q) -> exp2 -> two PV B-frags.
// ZERO cross-lane ops: S-output register order is used directly as the PV
// B-operand; V is stored (k_qkv) with the matching key permutation per
// 16-key group, so the MFMA k-slot sum runs over a consistently permuted
// key set -- mathematically identical, no permlane/shfl/LDS needed.
__device__ __forceinline__ void ptrans(const f32x16& sv, float& rsum,
                                       bf16x8& f0, bf16x8& f1) {
  float ps[16];
#pragma unroll
  for (int r = 0; r < 16; ++r) ps[r] = __builtin_exp2f(sv[r]);
  float rs = 0.f;
#pragma unroll
  for (int r = 0; r < 16; ++r) rs += ps[r];
  rsum += rs;
  bf16x8 a, b;
#pragma unroll
  for (int r = 0; r < 8; ++r) a[r] = (__bf16)ps[r];
#pragma unroll
  for (int r = 0; r < 8; ++r) b[r] = (__bf16)ps[8 + r];
  f0 = a; f1 = b;
}

// ---------------- K1a: hidden_states -> bf16 ----------------
__global__ __launch_bounds__(256) void k_split(const float* __restrict__ x,
                                               unsigned short* __restrict__ hi, int n4) {
  int i = blockIdx.x * blockDim.x + threadIdx.x;
  if (i >= n4) return;
  float4 v = ((const float4*)x)[i];
  ushort4 h;
  h.x = f2bf(v.x); h.y = f2bf(v.y); h.z = f2bf(v.z); h.w = f2bf(v.w);
  ((ushort4*)hi)[i] = h;
}

// ------------ K1b: transpose weights -> bf16 (fused, z selects W) ------------
__global__ __launch_bounds__(256) void k_wsplit(
    const float* __restrict__ Wq, const float* __restrict__ Wk,
    const float* __restrict__ Wv, const float* __restrict__ Wo,
    unsigned short* __restrict__ WtqH, unsigned short* __restrict__ WtkH,
    unsigned short* __restrict__ WtvH, unsigned short* __restrict__ WtoH) {
  const int z = blockIdx.z;
  const float* W = (z == 0) ? Wq : (z == 1) ? Wk : (z == 2) ? Wv : Wo;
  unsigned short* WtH = (z == 0) ? WtqH : (z == 1) ? WtkH : (z == 2) ? WtvH : WtoH;
  __shared__ float tile[32][33];
  const int bx = blockIdx.x, by = blockIdx.y;
  const int tx = threadIdx.x & 31, ty = threadIdx.x >> 5;
#pragma unroll
  for (int i = 0; i < 4; ++i)
    tile[ty + i * 8][tx] = W[(size_t)(by * 32 + ty + i * 8) * 1024 + bx * 32 + tx];
  __syncthreads();
#pragma unroll
  for (int i = 0; i < 4; ++i) {
    float v = tile[tx][ty + i * 8];
    WtH[(size_t)(bx * 32 + ty + i * 8) * 1024 + by * 32 + tx] = f2bf(v);
  }
}

// ---------------- K2: QKV GEMM, plain bf16, global_load_lds staging ----------------
__global__ __launch_bounds__(256, 2) void k_qkv(
    const unsigned short* __restrict__ hsH,
    const unsigned short* __restrict__ WqH, const unsigned short* __restrict__ WkH,
    const unsigned short* __restrict__ WvH, const float* __restrict__ freqs,
    unsigned short* __restrict__ qB, unsigned short* __restrict__ kB,
    unsigned short* __restrict__ vB) {
  __shared__ unsigned short Ah[128 * 32], Bh[128 * 32];  // 8KB each, 64B rows
  const int tid = threadIdx.x;
  const int bm = blockIdx.y, bn = blockIdx.x;
  const int w = bn >> 3;           // 0=q 1=k 2=v
  const int n0 = (bn & 7) * 128;
  const unsigned short* WH = (w == 0) ? WqH : (w == 1) ? WkH : WvH;
  const int lane = tid & 63, wave = tid >> 6;
  const int wm = (wave & 1) * 64, wn = (wave >> 1) * 64;
  const int l15 = lane & 15, lq = lane >> 4;

  f32x4 acc[4][4];
#pragma unroll
  for (int i = 0; i < 4; i++)
#pragma unroll
    for (int j = 0; j < 4; j++) acc[i][j] = (f32x4){0.f, 0.f, 0.f, 0.f};

  const char* baseA = (const char*)hsH + (size_t)(bm * 128) * 2048;
  const char* baseB = (const char*)WH + (size_t)n0 * 2048;
  const int off0 = tid << 4, row0 = off0 >> 6, seg0 = off0 & 63;
  const int off1 = (tid + 256) << 4, row1 = off1 >> 6, seg1 = off1 & 63;

  for (int k0 = 0; k0 < 1024; k0 += 32) {
    __syncthreads();
    gload_lds16(baseA + (size_t)row0 * 2048 + k0 * 2 + seg0, (char*)Ah + wave * 1024);
    gload_lds16(baseB + (size_t)row0 * 2048 + k0 * 2 + seg0, (char*)Bh + wave * 1024);
    gload_lds16(baseA + (size_t)row1 * 2048 + k0 * 2 + seg1,
                (char*)Ah + 4096 + wave * 1024);
    gload_lds16(baseB + (size_t)row1 * 2048 + k0 * 2 + seg1,
                (char*)Bh + 4096 + wave * 1024);
    __syncthreads();
    bf16x8 ah[4], bh[4];
#pragma unroll
    for (int i = 0; i < 4; ++i) {
      ah[i] = *(const bf16x8*)&Ah[(wm + i * 16 + l15) * 32 + lq * 8];
      bh[i] = *(const bf16x8*)&Bh[(wn + i * 16 + l15) * 32 + lq * 8];
    }
#pragma unroll
    for (int i = 0; i < 4; ++i)
#pragma unroll
      for (int j = 0; j < 4; ++j) acc[i][j] = MFMA16(ah[i], bh[j], acc[i][j]);
  }

  // epilogue: C/D layout col=lane&15, row=(lane>>4)*4+r. RoPE for q,k. V transposed.
  // Softmax scale * log2(e) folded into Q (f32, commutes with RoPE rotation).
  // V keys permuted within each 16-group (swap middle 4-blocks) to match the
  // S-register key order consumed directly by k_attn's PV MFMA.
  unsigned short* dst = (w == 0) ? qB : (w == 1) ? kB : vB;
#pragma unroll
  for (int i = 0; i < 4; ++i) {
#pragma unroll
    for (int j = 0; j < 4; ++j) {
      int colw = n0 + wn + j * 16 + l15;
      int h = colw >> 6, d = colw & 63;
#pragma unroll
      for (int r = 0; r < 4; ++r) {
        int rowg = bm * 128 + wm + i * 16 + lq * 4 + r;
        int s = rowg & 2047, b = rowg >> 11;
        float val = acc[i][j][r];
        if (w < 2) {
          float partner = __shfl_xor(val, 1);
          int jj = d >> 1;
          float cs = freqs[(s * 32 + jj) * 2 + 0];
          float sn = freqs[(s * 32 + jj) * 2 + 1];
          float res = (d & 1) ? (partner * sn + val * cs) : (val * cs - partner * sn);
          if (w == 0) res *= 0.18033688011112042f;  // 0.125 * log2(e)
          dst[(((size_t)(b * 16 + h)) * 2048 + s) * 64 + d] = f2bf(res);
        } else {
          // vB[bh][d][sp]: sp = s with 2-bit field (s>>2)&3 bit-reversed
          // (0->0, 1->2, 2->1, 3->3): swaps key blocks [4..7] <-> [8..11].
          int sp = (s & ~12) | ((s & 4) << 1) | ((s & 8) >> 1);
          dst[(((size_t)(b * 16 + h)) * 64 + d) * 2048 + sp] = f2bf(val);
        }
      }
    }
  }
}

// ------- K3: chunked attention, kb-split (512 keys/block) for 16 waves/CU -------
// Grid 1024: bid = b0 + 8*b1 + 64*b2; x(q-tile)=b1, gg = b0 + 8*b2 -> bh=gg&31,
// chunk=(gg>>5)&1, sub=gg>>6. All blocks of a (bh,chunk,sub) group share bid%8
// -> same XCD -> K/V L2 reuse; both subs of a (bh,chunk) also share bid%8 ->
// Q tiles shared in the same XCD L2.
// Each wave keeps 64 queries and walks 8 kb iters (512 keys): per-wave K/V
// reuse per load is UNCHANGED vs round 3 (the q-split mistake of round 1
// halved it); only the trip count halves -> 2x blocks -> 4 blocks/CU.
// Output: unnormalized bf16 partial O + f32 rsum per query; k_comb divides.
__global__ __launch_bounds__(256, 4) void k_attn(
    const unsigned short* __restrict__ qB, const unsigned short* __restrict__ kB,
    const unsigned short* __restrict__ vB,
    unsigned short* __restrict__ p00, unsigned short* __restrict__ p01,
    unsigned short* __restrict__ p10, unsigned short* __restrict__ p11,
    float* __restrict__ rsB) {
  const int tid = threadIdx.x, lane = tid & 63, wave = tid >> 6;
  const int l31 = lane & 31, lh = lane >> 5;
  const int bid = blockIdx.x;
  const int x = (bid >> 3) & 7;
  const int gg = (bid & 7) + 8 * (bid >> 6);
  const int bh = gg & 31;
  const int chunk = (gg >> 5) & 1;
  const int sub = gg >> 6;
  const int q0 = x * 256 + wave * 64;
  const int key0 = chunk * 1024 + sub * 512;
  const size_t base = (size_t)bh * 2048 * 64;

  // Q B-frags (pre-scaled in k_qkv): lane n=l31 -> query q0+qt*32+l31, k=ks*16+lh*8
  bf16x8 qf[2][4];
#pragma unroll
  for (int qt = 0; qt < 2; ++qt)
#pragma unroll
    for (int ks = 0; ks < 4; ++ks)
      qf[qt][ks] = *(const bf16x8*)(qB + base + (size_t)(q0 + qt * 32 + l31) * 64 +
                                    ks * 16 + lh * 8);

  const unsigned short* kp = kB + base + (size_t)key0 * 64 + l31 * 64 + lh * 8;
  const unsigned short* vp = vB + base + l31 * 2048 + key0 + lh * 8;

  // preload K for kb=0 (both 32-key halves)
  bf16x8 kfa[4], kfb[4];
#pragma unroll
  for (int ks = 0; ks < 4; ++ks) {
    kfa[ks] = *(const bf16x8*)(kp + ks * 16);
    kfb[ks] = *(const bf16x8*)(kp + 2048 + ks * 16);
  }
  kp += 4096;

  f32x16 o[2][2];  // [dt][qt]
#pragma unroll
  for (int a = 0; a < 2; ++a)
#pragma unroll
    for (int bq = 0; bq < 2; ++bq) o[a][bq] = fzero16();
  float rsum[2] = {0.f, 0.f};

  for (int kb = 0; kb < 8; ++kb) {
    // V^T frags up-front (consumed through the iteration -> time to land)
    bf16x8 vf[2][4];
#pragma unroll
    for (int dt = 0; dt < 2; ++dt)
#pragma unroll
      for (int ks = 0; ks < 4; ++ks)
        vf[dt][ks] = *(const bf16x8*)(vp + dt * 65536 + ks * 16);

    bf16x8 f0, f1;
    // ---- mt = 0 (keys +0..31) ----
    {
      f32x16 s0 = fzero16(), s1 = fzero16();
      __builtin_amdgcn_s_setprio(1);
#pragma unroll
      for (int ks = 0; ks < 4; ++ks) {
        s0 = MFMA32(kfa[ks], qf[0][ks], s0);
        s1 = MFMA32(kfa[ks], qf[1][ks], s1);
      }
      __builtin_amdgcn_s_setprio(0);
      // prefetch kb+1 first half into kfa (regs now consumed)
#pragma unroll
      for (int ks = 0; ks < 4; ++ks) kfa[ks] = *(const bf16x8*)(kp + ks * 16);
      ptrans(s0, rsum[0], f0, f1);
      __builtin_amdgcn_s_setprio(1);
      o[0][0] = MFMA32(vf[0][0], f0, o[0][0]);
      o[1][0] = MFMA32(vf[1][0], f0, o[1][0]);
      o[0][0] = MFMA32(vf[0][1], f1, o[0][0]);
      o[1][0] = MFMA32(vf[1][1], f1, o[1][0]);
      __builtin_amdgcn_s_setprio(0);
      ptrans(s1, rsum[1], f0, f1);
      __builtin_amdgcn_s_setprio(1);
      o[0][1] = MFMA32(vf[0][0], f0, o[0][1]);
      o[1][1] = MFMA32(vf[1][0], f0, o[1][1]);
      o[0][1] = MFMA32(vf[0][1], f1, o[0][1]);
      o[1][1] = MFMA32(vf[1][1], f1, o[1][1]);
      __builtin_amdgcn_s_setprio(0);
    }
    // ---- mt = 1 (keys +32..63) ----
    {
      f32x16 s0 = fzero16(), s1 = fzero16();
      __builtin_amdgcn_s_setprio(1);
#pragma unroll
      for (int ks = 0; ks < 4; ++ks) {
        s0 = MFMA32(kfb[ks], qf[0][ks], s0);
        s1 = MFMA32(kfb[ks], qf[1][ks], s1);
      }
      __builtin_amdgcn_s_setprio(0);
      // prefetch kb+1 second half into kfb
#pragma unroll
      for (int ks = 0; ks < 4; ++ks)
        kfb[ks] = *(const bf16x8*)(kp + 2048 + ks * 16);
      ptrans(s0, rsum[0], f0, f1);
      __builtin_amdgcn_s_setprio(1);
      o[0][0] = MFMA32(vf[0][2], f0, o[0][0]);
      o[1][0] = MFMA32(vf[1][2], f0, o[1][0]);
      o[0][0] = MFMA32(vf[0][3], f1, o[0][0]);
      o[1][0] = MFMA32(vf[1][3], f1, o[1][0]);
      __builtin_amdgcn_s_setprio(0);
      ptrans(s1, rsum[1], f0, f1);
      __builtin_amdgcn_s_setprio(1);
      o[0][1] = MFMA32(vf[0][2], f0, o[0][1]);
      o[1][1] = MFMA32(vf[1][2], f0, o[1][1]);
      o[0][1] = MFMA32(vf[0][3], f1, o[0][1]);
      o[1][1] = MFMA32(vf[1][3], f1, o[1][1]);
      __builtin_amdgcn_s_setprio(0);
    }
    kp += 4096;  // 64 keys * 64 elems
    vp += 64;    // 64 keys
  }

  // write unnormalized bf16 partial O + f32 rsum. O^T: d=dt*32+4*lh+8*g+t
  unsigned short* pB = chunk ? (sub ? p11 : p10) : (sub ? p01 : p00);
  float* rsp = rsB + (size_t)(chunk * 2 + sub) * 65536 + (size_t)bh * 2048;
  const int b = bh >> 4, h = bh & 15;
#pragma unroll
  for (int qt = 0; qt < 2; ++qt) {
    float lsum = rsum[qt] + __shfl_xor(rsum[qt], 32);
    int s = q0 + qt * 32 + l31;
    if (lh == 0) rsp[s] = lsum;
#pragma unroll
    for (int dt = 0; dt < 2; ++dt)
#pragma unroll
      for (int g = 0; g < 4; ++g) {
        int d = dt * 32 + 4 * lh + 8 * g;
        size_t idx = ((size_t)(b * 2048 + s)) * 1024 + h * 64 + d;
        ushort4 hv;
#pragma unroll
        for (int t = 0; t < 4; ++t)
          ((unsigned short*)&hv)[t] = f2bf(o[dt][qt][g * 4 + t]);
        *(ushort4*)(pB + idx) = hv;
      }
  }
}

// ------- K3b: combine: attnB = bf16((p00+p01)/r0 + (p10+p11)/r1) -------
__global__ __launch_bounds__(256) void k_comb(
    const unsigned short* __restrict__ p00, const unsigned short* __restrict__ p01,
    const unsigned short* __restrict__ p10, const unsigned short* __restrict__ p11,
    const float* __restrict__ rsB, unsigned short* __restrict__ outB, int n8) {
  int i = blockIdx.x * blockDim.x + threadIdx.x;
  if (i >= n8) return;
  int flat = i << 3;
  int b = flat >> 21;
  int s = (flat >> 10) & 2047;
  int h = (flat >> 6) & 15;
  int bhq = (b * 16 + h) * 2048 + s;
  float inv0 = 1.f / (rsB[bhq] + rsB[65536 + bhq]);
  float inv1 = 1.f / (rsB[131072 + bhq] + rsB[196608 + bhq]);
  uint4 a0 = ((const uint4*)p00)[i];
  uint4 a1 = ((const uint4*)p01)[i];
  uint4 b0 = ((const uint4*)p10)[i];
  uint4 b1 = ((const uint4*)p11)[i];
  uint4 r;
  const unsigned short* qa0 = (const unsigned short*)&a0;
  const unsigned short* qa1 = (const unsigned short*)&a1;
  const unsigned short* qb0 = (const unsigned short*)&b0;
  const unsigned short* qb1 = (const unsigned short*)&b1;
  unsigned short* pr = (unsigned short*)&r;
#pragma unroll
  for (int j = 0; j < 8; ++j)
    pr[j] = f2bf((bf2f(qa0[j]) + bf2f(qa1[j])) * inv0 +
                 (bf2f(qb0[j]) + bf2f(qb1[j])) * inv1);
  ((uint4*)outB)[i] = r;
}

// ---------------- K4: output projection, plain bf16, fp32 store ----------------
__global__ __launch_bounds__(256, 2) void k_out(const unsigned short* __restrict__ A,
                                                const unsigned short* __restrict__ B,
                                                float* __restrict__ out) {
  __shared__ unsigned short Ah[128 * 32], Bh[128 * 32];
  const int tid = threadIdx.x;
  const int bm = blockIdx.y, n0 = blockIdx.x * 128;
  const int lane = tid & 63, wave = tid >> 6;
  const int wm = (wave & 1) * 64, wn = (wave >> 1) * 64;
  const int l15 = lane & 15, lq = lane >> 4;

  f32x4 acc[4][4];
#pragma unroll
  for (int i = 0; i < 4; i++)
#pragma unroll
    for (int j = 0; j < 4; j++) acc[i][j] = (f32x4){0.f, 0.f, 0.f, 0.f};

  const char* baseA = (const char*)A + (size_t)(bm * 128) * 2048;
  const char* baseB = (const char*)B + (size_t)n0 * 2048;
  const int off0 = tid << 4, row0 = off0 >> 6, seg0 = off0 & 63;
  const int off1 = (tid + 256) << 4, row1 = off1 >> 6, seg1 = off1 & 63;

  for (int k0 = 0; k0 < 1024; k0 += 32) {
    __syncthreads();
    gload_lds16(baseA + (size_t)row0 * 2048 + k0 * 2 + seg0, (char*)Ah + wave * 1024);
    gload_lds16(baseB + (size_t)row0 * 2048 + k0 * 2 + seg0, (char*)Bh + wave * 1024);
    gload_lds16(baseA + (size_t)row1 * 2048 + k0 * 2 + seg1,
                (char*)Ah + 4096 + wave * 1024);
    gload_lds16(baseB + (size_t)row1 * 2048 + k0 * 2 + seg1,
                (char*)Bh + 4096 + wave * 1024);
    __syncthreads();
    bf16x8 ah[4], bh[4];
#pragma unroll
    for (int i = 0; i < 4; ++i) {
      ah[i] = *(const bf16x8*)&Ah[(wm + i * 16 + l15) * 32 + lq * 8];
      bh[i] = *(const bf16x8*)&Bh[(wn + i * 16 + l15) * 32 + lq * 8];
    }
#pragma unroll
    for (int i = 0; i < 4; ++i)
#pragma unroll
      for (int j = 0; j < 4; ++j) acc[i][j] = MFMA16(ah[i], bh[j], acc[i][j]);
  }
#pragma unroll
  for (int i = 0; i < 4; ++i)
#pragma unroll
    for (int j = 0; j < 4; ++j) {
      int colw = n0 + wn + j * 16 + l15;
#pragma unroll
      for (int r = 0; r < 4; ++r) {
        int rowg = bm * 128 + wm + i * 16 + lq * 4 + r;
        out[(size_t)rowg * 1024 + colw] = acc[i][j][r];
      }
    }
}

// ---------------- launch ----------------
extern "C" void kernel_launch(void* const* d_in, const int* in_sizes, int n_in,
                              void* d_out, int out_size, void* d_ws, size_t ws_size,
                              hipStream_t stream) {
  const float* hs = (const float*)d_in[0];
  const float* freqs = (const float*)d_in[1];
  const float* Wq = (const float*)d_in[2];
  const float* Wk = (const float*)d_in[3];
  const float* Wv = (const float*)d_in[4];
  const float* Wo = (const float*)d_in[5];
  float* out = (float*)d_out;

  const size_t MD = (size_t)4096 * 1024;
  const size_t WW = (size_t)1024 * 1024;
  unsigned short* hsH = (unsigned short*)d_ws;   // 8MB; dead after k_qkv -> p10
  unsigned short* WtqH = hsH + MD;
  unsigned short* WtkH = WtqH + WW;
  unsigned short* WtvH = WtkH + WW;
  unsigned short* WtoH = WtvH + WW;
  unsigned short* qB = WtoH + WW;                // dead after k_attn -> attnB
  unsigned short* kB = qB + MD;
  unsigned short* vB = kB + MD;
  unsigned short* p00 = vB + MD;
  unsigned short* p01 = p00 + MD;
  unsigned short* p11 = p01 + MD;
  float* rsB = (float*)(p11 + MD);               // 1MB (4 * 32 * 2048 f32)
  unsigned short* p10 = hsH;
  unsigned short* attnB = qB;

  k_split<<<4096, 256, 0, stream>>>(hs, hsH, (int)(MD / 4));
  k_wsplit<<<dim3(32, 32, 4), 256, 0, stream>>>(Wq, Wk, Wv, Wo,
                                                WtqH, WtkH, WtvH, WtoH);
  k_qkv<<<dim3(24, 32), 256, 0, stream>>>(hsH, WtqH, WtkH, WtvH, freqs, qB, kB, vB);
  k_attn<<<1024, 256, 0, stream>>>(qB, kB, vB, p00, p01, p10, p11, rsB);
  k_comb<<<2048, 256, 0, stream>>>(p00, p01, p10, p11, rsB, attnB, (int)(MD / 8));
  k_out<<<dim3(8, 32), 256, 0, stream>>>(attnB, WtoH, out);
}

// Round 5
// 292.569 us; speedup vs baseline: 2.2778x; 2.2778x over previous
//
#include <hip/hip_runtime.h>
#include <hip/hip_bf16.h>
#include <cstdint>

typedef __bf16 bf16x8 __attribute__((ext_vector_type(8)));
typedef float f32x4 __attribute__((ext_vector_type(4)));
typedef float f32x16 __attribute__((ext_vector_type(16)));

#define MFMA16(a, b, c) __builtin_amdgcn_mfma_f32_16x16x32_bf16(a, b, c, 0, 0, 0)
#define MFMA32(a, b, c) __builtin_amdgcn_mfma_f32_32x32x16_bf16(a, b, c, 0, 0, 0)

__device__ __forceinline__ void gload_lds16(const void* g, void* l) {
  __builtin_amdgcn_global_load_lds(
      (const __attribute__((address_space(1))) unsigned int*)g,
      (__attribute__((address_space(3))) unsigned int*)l, 16, 0, 0);
}

__device__ __forceinline__ unsigned short f2bf(float x) {
  union { float f; uint32_t u; } v; v.f = x;
  uint32_t r = v.u + 0x7fff + ((v.u >> 16) & 1);
  return (unsigned short)(r >> 16);
}
__device__ __forceinline__ float bf2f(unsigned short h) {
  union { float f; uint32_t u; } v; v.u = ((uint32_t)h) << 16;
  return v.f;
}
__device__ __forceinline__ f32x16 fzero16() {
  f32x16 v;
#pragma unroll
  for (int i = 0; i < 16; ++i) v[i] = 0.f;
  return v;
}

// S-tile (f32x16, pre-scaled by sc*log2e via Q) -> exp2 -> two PV B-frags.
// ZERO cross-lane ops: S-output register order is used directly as the PV
// B-operand; V is stored (k_qkv) with the matching key permutation per
// 16-key group, so the MFMA k-slot sum runs over a consistently permuted
// key set -- mathematically identical, no permlane/shfl/LDS needed.
__device__ __forceinline__ void ptrans(const f32x16& sv, float& rsum,
                                       bf16x8& f0, bf16x8& f1) {
  float ps[16];
#pragma unroll
  for (int r = 0; r < 16; ++r) ps[r] = __builtin_exp2f(sv[r]);
  float rs = 0.f;
#pragma unroll
  for (int r = 0; r < 16; ++r) rs += ps[r];
  rsum += rs;
  bf16x8 a, b;
#pragma unroll
  for (int r = 0; r < 8; ++r) a[r] = (__bf16)ps[r];
#pragma unroll
  for (int r = 0; r < 8; ++r) b[r] = (__bf16)ps[8 + r];
  f0 = a; f1 = b;
}

// ---------------- K1a: hidden_states -> bf16 ----------------
__global__ __launch_bounds__(256) void k_split(const float* __restrict__ x,
                                               unsigned short* __restrict__ hi, int n4) {
  int i = blockIdx.x * blockDim.x + threadIdx.x;
  if (i >= n4) return;
  float4 v = ((const float4*)x)[i];
  ushort4 h;
  h.x = f2bf(v.x); h.y = f2bf(v.y); h.z = f2bf(v.z); h.w = f2bf(v.w);
  ((ushort4*)hi)[i] = h;
}

// ------------ K1b: transpose weights -> bf16 (fused, z selects W) ------------
__global__ __launch_bounds__(256) void k_wsplit(
    const float* __restrict__ Wq, const float* __restrict__ Wk,
    const float* __restrict__ Wv, const float* __restrict__ Wo,
    unsigned short* __restrict__ WtqH, unsigned short* __restrict__ WtkH,
    unsigned short* __restrict__ WtvH, unsigned short* __restrict__ WtoH) {
  const int z = blockIdx.z;
  const float* W = (z == 0) ? Wq : (z == 1) ? Wk : (z == 2) ? Wv : Wo;
  unsigned short* WtH = (z == 0) ? WtqH : (z == 1) ? WtkH : (z == 2) ? WtvH : WtoH;
  __shared__ float tile[32][33];
  const int bx = blockIdx.x, by = blockIdx.y;
  const int tx = threadIdx.x & 31, ty = threadIdx.x >> 5;
#pragma unroll
  for (int i = 0; i < 4; ++i)
    tile[ty + i * 8][tx] = W[(size_t)(by * 32 + ty + i * 8) * 1024 + bx * 32 + tx];
  __syncthreads();
#pragma unroll
  for (int i = 0; i < 4; ++i) {
    float v = tile[tx][ty + i * 8];
    WtH[(size_t)(bx * 32 + ty + i * 8) * 1024 + by * 32 + tx] = f2bf(v);
  }
}

// ---------------- K2: QKV GEMM, plain bf16, global_load_lds staging ----------------
__global__ __launch_bounds__(256, 2) void k_qkv(
    const unsigned short* __restrict__ hsH,
    const unsigned short* __restrict__ WqH, const unsigned short* __restrict__ WkH,
    const unsigned short* __restrict__ WvH, const float* __restrict__ freqs,
    unsigned short* __restrict__ qB, unsigned short* __restrict__ kB,
    unsigned short* __restrict__ vB) {
  __shared__ unsigned short Ah[128 * 32], Bh[128 * 32];  // 8KB each, 64B rows
  const int tid = threadIdx.x;
  const int bm = blockIdx.y, bn = blockIdx.x;
  const int w = bn >> 3;           // 0=q 1=k 2=v
  const int n0 = (bn & 7) * 128;
  const unsigned short* WH = (w == 0) ? WqH : (w == 1) ? WkH : WvH;
  const int lane = tid & 63, wave = tid >> 6;
  const int wm = (wave & 1) * 64, wn = (wave >> 1) * 64;
  const int l15 = lane & 15, lq = lane >> 4;

  f32x4 acc[4][4];
#pragma unroll
  for (int i = 0; i < 4; i++)
#pragma unroll
    for (int j = 0; j < 4; j++) acc[i][j] = (f32x4){0.f, 0.f, 0.f, 0.f};

  const char* baseA = (const char*)hsH + (size_t)(bm * 128) * 2048;
  const char* baseB = (const char*)WH + (size_t)n0 * 2048;
  const int off0 = tid << 4, row0 = off0 >> 6, seg0 = off0 & 63;
  const int off1 = (tid + 256) << 4, row1 = off1 >> 6, seg1 = off1 & 63;

  for (int k0 = 0; k0 < 1024; k0 += 32) {
    __syncthreads();
    gload_lds16(baseA + (size_t)row0 * 2048 + k0 * 2 + seg0, (char*)Ah + wave * 1024);
    gload_lds16(baseB + (size_t)row0 * 2048 + k0 * 2 + seg0, (char*)Bh + wave * 1024);
    gload_lds16(baseA + (size_t)row1 * 2048 + k0 * 2 + seg1,
                (char*)Ah + 4096 + wave * 1024);
    gload_lds16(baseB + (size_t)row1 * 2048 + k0 * 2 + seg1,
                (char*)Bh + 4096 + wave * 1024);
    __syncthreads();
    bf16x8 ah[4], bh[4];
#pragma unroll
    for (int i = 0; i < 4; ++i) {
      ah[i] = *(const bf16x8*)&Ah[(wm + i * 16 + l15) * 32 + lq * 8];
      bh[i] = *(const bf16x8*)&Bh[(wn + i * 16 + l15) * 32 + lq * 8];
    }
#pragma unroll
    for (int i = 0; i < 4; ++i)
#pragma unroll
      for (int j = 0; j < 4; ++j) acc[i][j] = MFMA16(ah[i], bh[j], acc[i][j]);
  }

  // epilogue: C/D layout col=lane&15, row=(lane>>4)*4+r. RoPE for q,k. V transposed.
  // Softmax scale * log2(e) folded into Q (f32, commutes with RoPE rotation).
  // V keys permuted within each 16-group (swap middle 4-blocks) to match the
  // S-register key order consumed directly by k_attn's PV MFMA.
  unsigned short* dst = (w == 0) ? qB : (w == 1) ? kB : vB;
#pragma unroll
  for (int i = 0; i < 4; ++i) {
#pragma unroll
    for (int j = 0; j < 4; ++j) {
      int colw = n0 + wn + j * 16 + l15;
      int h = colw >> 6, d = colw & 63;
#pragma unroll
      for (int r = 0; r < 4; ++r) {
        int rowg = bm * 128 + wm + i * 16 + lq * 4 + r;
        int s = rowg & 2047, b = rowg >> 11;
        float val = acc[i][j][r];
        if (w < 2) {
          float partner = __shfl_xor(val, 1);
          int jj = d >> 1;
          float cs = freqs[(s * 32 + jj) * 2 + 0];
          float sn = freqs[(s * 32 + jj) * 2 + 1];
          float res = (d & 1) ? (partner * sn + val * cs) : (val * cs - partner * sn);
          if (w == 0) res *= 0.18033688011112042f;  // 0.125 * log2(e)
          dst[(((size_t)(b * 16 + h)) * 2048 + s) * 64 + d] = f2bf(res);
        } else {
          // vB[bh][d][sp]: sp = s with 2-bit field (s>>2)&3 bit-reversed
          // (0->0, 1->2, 2->1, 3->3): swaps key blocks [4..7] <-> [8..11].
          int sp = (s & ~12) | ((s & 4) << 1) | ((s & 8) >> 1);
          dst[(((size_t)(b * 16 + h)) * 64 + d) * 2048 + sp] = f2bf(val);
        }
      }
    }
  }
}

// ------- K3: chunked attention, kb-split (512 keys/block), 4 blocks/CU -------
// Grid 1024: bid = b0 + 8*b1 + 64*b2; x(q-tile)=b1, gg = b0 + 8*b2 -> bh=gg&31,
// chunk=(gg>>5)&1, sub=gg>>6. Blocks of a (bh,chunk,sub) group share bid%8 ->
// same XCD -> K/V L2 reuse.
// launch_bounds (256,2): round 4 proved (256,4) caps the UNIFIED VGPR+AGPR
// file at 128/wave -> full spill to scratch (FETCH 16->897MB, 5.5x slower).
// Actual unified usage ~190/wave allows 4 waves/SIMD through the hardware
// allocator with no compiler cap; occupancy comes from grid (1024 blocks).
// Output: unnormalized bf16 partial O + f32 rsum per query; k_comb divides.
__global__ __launch_bounds__(256, 2) void k_attn(
    const unsigned short* __restrict__ qB, const unsigned short* __restrict__ kB,
    const unsigned short* __restrict__ vB,
    unsigned short* __restrict__ p00, unsigned short* __restrict__ p01,
    unsigned short* __restrict__ p10, unsigned short* __restrict__ p11,
    float* __restrict__ rsB) {
  const int tid = threadIdx.x, lane = tid & 63, wave = tid >> 6;
  const int l31 = lane & 31, lh = lane >> 5;
  const int bid = blockIdx.x;
  const int x = (bid >> 3) & 7;
  const int gg = (bid & 7) + 8 * (bid >> 6);
  const int bh = gg & 31;
  const int chunk = (gg >> 5) & 1;
  const int sub = gg >> 6;
  const int q0 = x * 256 + wave * 64;
  const int key0 = chunk * 1024 + sub * 512;
  const size_t base = (size_t)bh * 2048 * 64;

  // Q B-frags (pre-scaled in k_qkv): lane n=l31 -> query q0+qt*32+l31, k=ks*16+lh*8
  bf16x8 qf[2][4];
#pragma unroll
  for (int qt = 0; qt < 2; ++qt)
#pragma unroll
    for (int ks = 0; ks < 4; ++ks)
      qf[qt][ks] = *(const bf16x8*)(qB + base + (size_t)(q0 + qt * 32 + l31) * 64 +
                                    ks * 16 + lh * 8);

  const unsigned short* kp = kB + base + (size_t)key0 * 64 + l31 * 64 + lh * 8;
  const unsigned short* vp = vB + base + l31 * 2048 + key0 + lh * 8;

  // preload K for kb=0 (both 32-key halves)
  bf16x8 kfa[4], kfb[4];
#pragma unroll
  for (int ks = 0; ks < 4; ++ks) {
    kfa[ks] = *(const bf16x8*)(kp + ks * 16);
    kfb[ks] = *(const bf16x8*)(kp + 2048 + ks * 16);
  }
  kp += 4096;

  f32x16 o[2][2];  // [dt][qt]
#pragma unroll
  for (int a = 0; a < 2; ++a)
#pragma unroll
    for (int bq = 0; bq < 2; ++bq) o[a][bq] = fzero16();
  float rsum[2] = {0.f, 0.f};

  for (int kb = 0; kb < 8; ++kb) {
    // V^T frags up-front (consumed through the iteration -> time to land)
    bf16x8 vf[2][4];
#pragma unroll
    for (int dt = 0; dt < 2; ++dt)
#pragma unroll
      for (int ks = 0; ks < 4; ++ks)
        vf[dt][ks] = *(const bf16x8*)(vp + dt * 65536 + ks * 16);

    bf16x8 f0, f1;
    // ---- mt = 0 (keys +0..31) ----
    {
      f32x16 s0 = fzero16(), s1 = fzero16();
      __builtin_amdgcn_s_setprio(1);
#pragma unroll
      for (int ks = 0; ks < 4; ++ks) {
        s0 = MFMA32(kfa[ks], qf[0][ks], s0);
        s1 = MFMA32(kfa[ks], qf[1][ks], s1);
      }
      __builtin_amdgcn_s_setprio(0);
      // prefetch kb+1 first half into kfa (regs now consumed)
#pragma unroll
      for (int ks = 0; ks < 4; ++ks) kfa[ks] = *(const bf16x8*)(kp + ks * 16);
      ptrans(s0, rsum[0], f0, f1);
      __builtin_amdgcn_s_setprio(1);
      o[0][0] = MFMA32(vf[0][0], f0, o[0][0]);
      o[1][0] = MFMA32(vf[1][0], f0, o[1][0]);
      o[0][0] = MFMA32(vf[0][1], f1, o[0][0]);
      o[1][0] = MFMA32(vf[1][1], f1, o[1][0]);
      __builtin_amdgcn_s_setprio(0);
      ptrans(s1, rsum[1], f0, f1);
      __builtin_amdgcn_s_setprio(1);
      o[0][1] = MFMA32(vf[0][0], f0, o[0][1]);
      o[1][1] = MFMA32(vf[1][0], f0, o[1][1]);
      o[0][1] = MFMA32(vf[0][1], f1, o[0][1]);
      o[1][1] = MFMA32(vf[1][1], f1, o[1][1]);
      __builtin_amdgcn_s_setprio(0);
    }
    // ---- mt = 1 (keys +32..63) ----
    {
      f32x16 s0 = fzero16(), s1 = fzero16();
      __builtin_amdgcn_s_setprio(1);
#pragma unroll
      for (int ks = 0; ks < 4; ++ks) {
        s0 = MFMA32(kfb[ks], qf[0][ks], s0);
        s1 = MFMA32(kfb[ks], qf[1][ks], s1);
      }
      __builtin_amdgcn_s_setprio(0);
      // prefetch kb+1 second half into kfb
#pragma unroll
      for (int ks = 0; ks < 4; ++ks)
        kfb[ks] = *(const bf16x8*)(kp + 2048 + ks * 16);
      ptrans(s0, rsum[0], f0, f1);
      __builtin_amdgcn_s_setprio(1);
      o[0][0] = MFMA32(vf[0][2], f0, o[0][0]);
      o[1][0] = MFMA32(vf[1][2], f0, o[1][0]);
      o[0][0] = MFMA32(vf[0][3], f1, o[0][0]);
      o[1][0] = MFMA32(vf[1][3], f1, o[1][0]);
      __builtin_amdgcn_s_setprio(0);
      ptrans(s1, rsum[1], f0, f1);
      __builtin_amdgcn_s_setprio(1);
      o[0][1] = MFMA32(vf[0][2], f0, o[0][1]);
      o[1][1] = MFMA32(vf[1][2], f0, o[1][1]);
      o[0][1] = MFMA32(vf[0][3], f1, o[0][1]);
      o[1][1] = MFMA32(vf[1][3], f1, o[1][1]);
      __builtin_amdgcn_s_setprio(0);
    }
    kp += 4096;  // 64 keys * 64 elems
    vp += 64;    // 64 keys
  }

  // write unnormalized bf16 partial O + f32 rsum. O^T: d=dt*32+4*lh+8*g+t
  unsigned short* pB = chunk ? (sub ? p11 : p10) : (sub ? p01 : p00);
  float* rsp = rsB + (size_t)(chunk * 2 + sub) * 65536 + (size_t)bh * 2048;
  const int b = bh >> 4, h = bh & 15;
#pragma unroll
  for (int qt = 0; qt < 2; ++qt) {
    float lsum = rsum[qt] + __shfl_xor(rsum[qt], 32);
    int s = q0 + qt * 32 + l31;
    if (lh == 0) rsp[s] = lsum;
#pragma unroll
    for (int dt = 0; dt < 2; ++dt)
#pragma unroll
      for (int g = 0; g < 4; ++g) {
        int d = dt * 32 + 4 * lh + 8 * g;
        size_t idx = ((size_t)(b * 2048 + s)) * 1024 + h * 64 + d;
        ushort4 hv;
#pragma unroll
        for (int t = 0; t < 4; ++t)
          ((unsigned short*)&hv)[t] = f2bf(o[dt][qt][g * 4 + t]);
        *(ushort4*)(pB + idx) = hv;
      }
  }
}

// ------- K3b: combine: attnB = bf16((p00+p01)/r0 + (p10+p11)/r1) -------
__global__ __launch_bounds__(256) void k_comb(
    const unsigned short* __restrict__ p00, const unsigned short* __restrict__ p01,
    const unsigned short* __restrict__ p10, const unsigned short* __restrict__ p11,
    const float* __restrict__ rsB, unsigned short* __restrict__ outB, int n8) {
  int i = blockIdx.x * blockDim.x + threadIdx.x;
  if (i >= n8) return;
  int flat = i << 3;
  int b = flat >> 21;
  int s = (flat >> 10) & 2047;
  int h = (flat >> 6) & 15;
  int bhq = (b * 16 + h) * 2048 + s;
  float inv0 = 1.f / (rsB[bhq] + rsB[65536 + bhq]);
  float inv1 = 1.f / (rsB[131072 + bhq] + rsB[196608 + bhq]);
  uint4 a0 = ((const uint4*)p00)[i];
  uint4 a1 = ((const uint4*)p01)[i];
  uint4 b0 = ((const uint4*)p10)[i];
  uint4 b1 = ((const uint4*)p11)[i];
  uint4 r;
  const unsigned short* qa0 = (const unsigned short*)&a0;
  const unsigned short* qa1 = (const unsigned short*)&a1;
  const unsigned short* qb0 = (const unsigned short*)&b0;
  const unsigned short* qb1 = (const unsigned short*)&b1;
  unsigned short* pr = (unsigned short*)&r;
#pragma unroll
  for (int j = 0; j < 8; ++j)
    pr[j] = f2bf((bf2f(qa0[j]) + bf2f(qa1[j])) * inv0 +
                 (bf2f(qb0[j]) + bf2f(qb1[j])) * inv1);
  ((uint4*)outB)[i] = r;
}

// ---------------- K4: output projection, plain bf16, fp32 store ----------------
__global__ __launch_bounds__(256, 2) void k_out(const unsigned short* __restrict__ A,
                                                const unsigned short* __restrict__ B,
                                                float* __restrict__ out) {
  __shared__ unsigned short Ah[128 * 32], Bh[128 * 32];
  const int tid = threadIdx.x;
  const int bm = blockIdx.y, n0 = blockIdx.x * 128;
  const int lane = tid & 63, wave = tid >> 6;
  const int wm = (wave & 1) * 64, wn = (wave >> 1) * 64;
  const int l15 = lane & 15, lq = lane >> 4;

  f32x4 acc[4][4];
#pragma unroll
  for (int i = 0; i < 4; i++)
#pragma unroll
    for (int j = 0; j < 4; j++) acc[i][j] = (f32x4){0.f, 0.f, 0.f, 0.f};

  const char* baseA = (const char*)A + (size_t)(bm * 128) * 2048;
  const char* baseB = (const char*)B + (size_t)n0 * 2048;
  const int off0 = tid << 4, row0 = off0 >> 6, seg0 = off0 & 63;
  const int off1 = (tid + 256) << 4, row1 = off1 >> 6, seg1 = off1 & 63;

  for (int k0 = 0; k0 < 1024; k0 += 32) {
    __syncthreads();
    gload_lds16(baseA + (size_t)row0 * 2048 + k0 * 2 + seg0, (char*)Ah + wave * 1024);
    gload_lds16(baseB + (size_t)row0 * 2048 + k0 * 2 + seg0, (char*)Bh + wave * 1024);
    gload_lds16(baseA + (size_t)row1 * 2048 + k0 * 2 + seg1,
                (char*)Ah + 4096 + wave * 1024);
    gload_lds16(baseB + (size_t)row1 * 2048 + k0 * 2 + seg1,
                (char*)Bh + 4096 + wave * 1024);
    __syncthreads();
    bf16x8 ah[4], bh[4];
#pragma unroll
    for (int i = 0; i < 4; ++i) {
      ah[i] = *(const bf16x8*)&Ah[(wm + i * 16 + l15) * 32 + lq * 8];
      bh[i] = *(const bf16x8*)&Bh[(wn + i * 16 + l15) * 32 + lq * 8];
    }
#pragma unroll
    for (int i = 0; i < 4; ++i)
#pragma unroll
      for (int j = 0; j < 4; ++j) acc[i][j] = MFMA16(ah[i], bh[j], acc[i][j]);
  }
#pragma unroll
  for (int i = 0; i < 4; ++i)
#pragma unroll
    for (int j = 0; j < 4; ++j) {
      int colw = n0 + wn + j * 16 + l15;
#pragma unroll
      for (int r = 0; r < 4; ++r) {
        int rowg = bm * 128 + wm + i * 16 + lq * 4 + r;
        out[(size_t)rowg * 1024 + colw] = acc[i][j][r];
      }
    }
}

// ---------------- launch ----------------
extern "C" void kernel_launch(void* const* d_in, const int* in_sizes, int n_in,
                              void* d_out, int out_size, void* d_ws, size_t ws_size,
                              hipStream_t stream) {
  const float* hs = (const float*)d_in[0];
  const float* freqs = (const float*)d_in[1];
  const float* Wq = (const float*)d_in[2];
  const float* Wk = (const float*)d_in[3];
  const float* Wv = (const float*)d_in[4];
  const float* Wo = (const float*)d_in[5];
  float* out = (float*)d_out;

  const size_t MD = (size_t)4096 * 1024;
  const size_t WW = (size_t)1024 * 1024;
  unsigned short* hsH = (unsigned short*)d_ws;   // 8MB; dead after k_qkv -> p10
  unsigned short* WtqH = hsH + MD;
  unsigned short* WtkH = WtqH + WW;
  unsigned short* WtvH = WtkH + WW;
  unsigned short* WtoH = WtvH + WW;
  unsigned short* qB = WtoH + WW;                // dead after k_attn -> attnB
  unsigned short* kB = qB + MD;
  unsigned short* vB = kB + MD;
  unsigned short* p00 = vB + MD;
  unsigned short* p01 = p00 + MD;
  unsigned short* p11 = p01 + MD;
  float* rsB = (float*)(p11 + MD);               // 1MB (4 * 32 * 2048 f32)
  unsigned short* p10 = hsH;
  unsigned short* attnB = qB;

  k_split<<<4096, 256, 0, stream>>>(hs, hsH, (int)(MD / 4));
  k_wsplit<<<dim3(32, 32, 4), 256, 0, stream>>>(Wq, Wk, Wv, Wo,
                                                WtqH, WtkH, WtvH, WtoH);
  k_qkv<<<dim3(24, 32), 256, 0, stream>>>(hsH, WtqH, WtkH, WtvH, freqs, qB, kB, vB);
  k_attn<<<1024, 256, 0, stream>>>(qB, kB, vB, p00, p01, p10, p11, rsB);
  k_comb<<<2048, 256, 0, stream>>>(p00, p01, p10, p11, rsB, attnB, (int)(MD / 8));
  k_out<<<dim3(8, 32), 256, 0, stream>>>(attnB, WtoH, out);
}

// Round 6
// 233.132 us; speedup vs baseline: 2.8585x; 1.2549x over previous
//
#include <hip/hip_runtime.h>
#include <hip/hip_bf16.h>
#include <cstdint>

typedef __bf16 bf16x8 __attribute__((ext_vector_type(8)));
typedef float f32x4 __attribute__((ext_vector_type(4)));
typedef float f32x16 __attribute__((ext_vector_type(16)));

#define MFMA16(a, b, c) __builtin_amdgcn_mfma_f32_16x16x32_bf16(a, b, c, 0, 0, 0)
#define MFMA32(a, b, c) __builtin_amdgcn_mfma_f32_32x32x16_bf16(a, b, c, 0, 0, 0)

__device__ __forceinline__ void gload_lds16(const void* g, void* l) {
  __builtin_amdgcn_global_load_lds(
      (const __attribute__((address_space(1))) unsigned int*)g,
      (__attribute__((address_space(3))) unsigned int*)l, 16, 0, 0);
}

__device__ __forceinline__ unsigned short f2bf(float x) {
  union { float f; uint32_t u; } v; v.f = x;
  uint32_t r = v.u + 0x7fff + ((v.u >> 16) & 1);
  return (unsigned short)(r >> 16);
}
__device__ __forceinline__ float bf2f(unsigned short h) {
  union { float f; uint32_t u; } v; v.u = ((uint32_t)h) << 16;
  return v.f;
}
__device__ __forceinline__ f32x16 fzero16() {
  f32x16 v;
#pragma unroll
  for (int i = 0; i < 16; ++i) v[i] = 0.f;
  return v;
}

// S-tile (f32x16, pre-scaled by sc*log2e via Q) -> exp2 -> two PV B-frags.
// ZERO cross-lane ops: S-output register order is used directly as the PV
// B-operand; V is stored (k_qkv) with the matching key permutation per
// 16-key group, so the MFMA k-slot sum runs over a consistently permuted
// key set -- mathematically identical, no permlane/shfl/LDS needed.
__device__ __forceinline__ void ptrans(const f32x16& sv, float& rsum,
                                       bf16x8& f0, bf16x8& f1) {
  float ps[16];
#pragma unroll
  for (int r = 0; r < 16; ++r) ps[r] = __builtin_exp2f(sv[r]);
  float rs = 0.f;
#pragma unroll
  for (int r = 0; r < 16; ++r) rs += ps[r];
  rsum += rs;
  bf16x8 a, b;
#pragma unroll
  for (int r = 0; r < 8; ++r) a[r] = (__bf16)ps[r];
#pragma unroll
  for (int r = 0; r < 8; ++r) b[r] = (__bf16)ps[8 + r];
  f0 = a; f1 = b;
}

// ---------------- K1a: hidden_states -> bf16 ----------------
__global__ __launch_bounds__(256) void k_split(const float* __restrict__ x,
                                               unsigned short* __restrict__ hi, int n4) {
  int i = blockIdx.x * blockDim.x + threadIdx.x;
  if (i >= n4) return;
  float4 v = ((const float4*)x)[i];
  ushort4 h;
  h.x = f2bf(v.x); h.y = f2bf(v.y); h.z = f2bf(v.z); h.w = f2bf(v.w);
  ((ushort4*)hi)[i] = h;
}

// ------------ K1b: transpose weights -> bf16 (fused, z selects W) ------------
__global__ __launch_bounds__(256) void k_wsplit(
    const float* __restrict__ Wq, const float* __restrict__ Wk,
    const float* __restrict__ Wv, const float* __restrict__ Wo,
    unsigned short* __restrict__ WtqH, unsigned short* __restrict__ WtkH,
    unsigned short* __restrict__ WtvH, unsigned short* __restrict__ WtoH) {
  const int z = blockIdx.z;
  const float* W = (z == 0) ? Wq : (z == 1) ? Wk : (z == 2) ? Wv : Wo;
  unsigned short* WtH = (z == 0) ? WtqH : (z == 1) ? WtkH : (z == 2) ? WtvH : WtoH;
  __shared__ float tile[32][33];
  const int bx = blockIdx.x, by = blockIdx.y;
  const int tx = threadIdx.x & 31, ty = threadIdx.x >> 5;
#pragma unroll
  for (int i = 0; i < 4; ++i)
    tile[ty + i * 8][tx] = W[(size_t)(by * 32 + ty + i * 8) * 1024 + bx * 32 + tx];
  __syncthreads();
#pragma unroll
  for (int i = 0; i < 4; ++i) {
    float v = tile[tx][ty + i * 8];
    WtH[(size_t)(bx * 32 + ty + i * 8) * 1024 + by * 32 + tx] = f2bf(v);
  }
}

// ---------------- K2: QKV GEMM, plain bf16, global_load_lds staging ----------------
__global__ __launch_bounds__(256, 2) void k_qkv(
    const unsigned short* __restrict__ hsH,
    const unsigned short* __restrict__ WqH, const unsigned short* __restrict__ WkH,
    const unsigned short* __restrict__ WvH, const float* __restrict__ freqs,
    unsigned short* __restrict__ qB, unsigned short* __restrict__ kB,
    unsigned short* __restrict__ vB) {
  __shared__ unsigned short Ah[128 * 32], Bh[128 * 32];  // 8KB each, 64B rows
  const int tid = threadIdx.x;
  const int bm = blockIdx.y, bn = blockIdx.x;
  const int w = bn >> 3;           // 0=q 1=k 2=v
  const int n0 = (bn & 7) * 128;
  const unsigned short* WH = (w == 0) ? WqH : (w == 1) ? WkH : WvH;
  const int lane = tid & 63, wave = tid >> 6;
  const int wm = (wave & 1) * 64, wn = (wave >> 1) * 64;
  const int l15 = lane & 15, lq = lane >> 4;

  f32x4 acc[4][4];
#pragma unroll
  for (int i = 0; i < 4; i++)
#pragma unroll
    for (int j = 0; j < 4; j++) acc[i][j] = (f32x4){0.f, 0.f, 0.f, 0.f};

  const char* baseA = (const char*)hsH + (size_t)(bm * 128) * 2048;
  const char* baseB = (const char*)WH + (size_t)n0 * 2048;
  const int off0 = tid << 4, row0 = off0 >> 6, seg0 = off0 & 63;
  const int off1 = (tid + 256) << 4, row1 = off1 >> 6, seg1 = off1 & 63;

  for (int k0 = 0; k0 < 1024; k0 += 32) {
    __syncthreads();
    gload_lds16(baseA + (size_t)row0 * 2048 + k0 * 2 + seg0, (char*)Ah + wave * 1024);
    gload_lds16(baseB + (size_t)row0 * 2048 + k0 * 2 + seg0, (char*)Bh + wave * 1024);
    gload_lds16(baseA + (size_t)row1 * 2048 + k0 * 2 + seg1,
                (char*)Ah + 4096 + wave * 1024);
    gload_lds16(baseB + (size_t)row1 * 2048 + k0 * 2 + seg1,
                (char*)Bh + 4096 + wave * 1024);
    __syncthreads();
    bf16x8 ah[4], bh[4];
#pragma unroll
    for (int i = 0; i < 4; ++i) {
      ah[i] = *(const bf16x8*)&Ah[(wm + i * 16 + l15) * 32 + lq * 8];
      bh[i] = *(const bf16x8*)&Bh[(wn + i * 16 + l15) * 32 + lq * 8];
    }
#pragma unroll
    for (int i = 0; i < 4; ++i)
#pragma unroll
      for (int j = 0; j < 4; ++j) acc[i][j] = MFMA16(ah[i], bh[j], acc[i][j]);
  }

  // epilogue: C/D layout col=lane&15, row=(lane>>4)*4+r. RoPE for q,k. V transposed.
  // Softmax scale * log2(e) folded into Q (f32, commutes with RoPE rotation).
  // V keys permuted within each 16-group (swap middle 4-blocks) to match the
  // S-register key order consumed directly by k_attn's PV MFMA.
  unsigned short* dst = (w == 0) ? qB : (w == 1) ? kB : vB;
#pragma unroll
  for (int i = 0; i < 4; ++i) {
#pragma unroll
    for (int j = 0; j < 4; ++j) {
      int colw = n0 + wn + j * 16 + l15;
      int h = colw >> 6, d = colw & 63;
#pragma unroll
      for (int r = 0; r < 4; ++r) {
        int rowg = bm * 128 + wm + i * 16 + lq * 4 + r;
        int s = rowg & 2047, b = rowg >> 11;
        float val = acc[i][j][r];
        if (w < 2) {
          float partner = __shfl_xor(val, 1);
          int jj = d >> 1;
          float cs = freqs[(s * 32 + jj) * 2 + 0];
          float sn = freqs[(s * 32 + jj) * 2 + 1];
          float res = (d & 1) ? (partner * sn + val * cs) : (val * cs - partner * sn);
          if (w == 0) res *= 0.18033688011112042f;  // 0.125 * log2(e)
          dst[(((size_t)(b * 16 + h)) * 2048 + s) * 64 + d] = f2bf(res);
        } else {
          // vB[bh][d][sp]: sp = s with 2-bit field (s>>2)&3 bit-reversed
          // (0->0, 1->2, 2->1, 3->3): swaps key blocks [4..7] <-> [8..11].
          int sp = (s & ~12) | ((s & 4) << 1) | ((s & 8) >> 1);
          dst[(((size_t)(b * 16 + h)) * 64 + d) * 2048 + sp] = f2bf(val);
        }
      }
    }
  }
}

// ------- K3: chunked attention, round-3 skeleton + within-wave ILP reorder -------
// Grid 512; id = xcd + 8*(x + 8*hi), group g=(bh,chunk)=xcd+8*hi so all 8
// q-tile blocks of a (bh,chunk) share ids mod 8 -> same XCD -> K/V L2 reuse.
// Per-kb phases reordered for dual-pipe overlap (in-order issue, two pipes):
//   [16 S-MFMAs both mt halves] [K prefetch] [ptrans mt0] [PV mt0 MFMAs]
//   [ptrans mt1 issues under in-flight PV mt0] [PV mt1]
// Both mt S-tiles live simultaneously (+32 f32 regs vs round 3) -- stays under
// the (256,2) unified 256-reg cap. Rounds 1/4/5 proved occupancy restructures
// (q-split, kb-split, launch_bounds(,4)) all lose on traffic/spill; 2 blocks/CU
// with better ILP is the winning direction.
__global__ __launch_bounds__(256, 2) void k_attn(
    const unsigned short* __restrict__ qB, const unsigned short* __restrict__ kB,
    const unsigned short* __restrict__ vB,
    unsigned short* __restrict__ c0, unsigned short* __restrict__ c1) {
  const int tid = threadIdx.x, lane = tid & 63, wave = tid >> 6;
  const int l31 = lane & 31, lh = lane >> 5;
  const int bid = blockIdx.x;
  const int x = (bid >> 3) & 7;
  const int gg = (bid & 7) + 8 * (bid >> 6);
  const int bh = gg & 31;
  const int chunk = gg >> 5;
  const int q0 = x * 256 + wave * 64;
  const size_t base = (size_t)bh * 2048 * 64;

  // Q B-frags (pre-scaled in k_qkv): lane n=l31 -> query q0+qt*32+l31, k=ks*16+lh*8
  bf16x8 qf[2][4];
#pragma unroll
  for (int qt = 0; qt < 2; ++qt)
#pragma unroll
    for (int ks = 0; ks < 4; ++ks)
      qf[qt][ks] = *(const bf16x8*)(qB + base + (size_t)(q0 + qt * 32 + l31) * 64 +
                                    ks * 16 + lh * 8);

  const unsigned short* kp = kB + base + (size_t)chunk * 1024 * 64 + l31 * 64 + lh * 8;
  const unsigned short* vp = vB + base + l31 * 2048 + chunk * 1024 + lh * 8;

  // preload K for kb=0 (both 32-key halves)
  bf16x8 kfa[4], kfb[4];
#pragma unroll
  for (int ks = 0; ks < 4; ++ks) {
    kfa[ks] = *(const bf16x8*)(kp + ks * 16);
    kfb[ks] = *(const bf16x8*)(kp + 2048 + ks * 16);
  }
  kp += 4096;

  f32x16 o[2][2];  // [dt][qt]
#pragma unroll
  for (int a = 0; a < 2; ++a)
#pragma unroll
    for (int bq = 0; bq < 2; ++bq) o[a][bq] = fzero16();
  float rsum[2] = {0.f, 0.f};

  for (int kb = 0; kb < 16; ++kb) {
    // V^T frags up-front (consumed at iter end -> full S/exp phase to land)
    bf16x8 vf[2][4];
#pragma unroll
    for (int dt = 0; dt < 2; ++dt)
#pragma unroll
      for (int ks = 0; ks < 4; ++ks)
        vf[dt][ks] = *(const bf16x8*)(vp + dt * 65536 + ks * 16);

    // ---- phase 1: all 16 S-MFMAs (both mt halves, both qt tiles) ----
    f32x16 sA0 = fzero16(), sA1 = fzero16();  // mt0
    f32x16 sB0 = fzero16(), sB1 = fzero16();  // mt1
    __builtin_amdgcn_s_setprio(1);
#pragma unroll
    for (int ks = 0; ks < 4; ++ks) {
      sA0 = MFMA32(kfa[ks], qf[0][ks], sA0);
      sA1 = MFMA32(kfa[ks], qf[1][ks], sA1);
    }
#pragma unroll
    for (int ks = 0; ks < 4; ++ks) {
      sB0 = MFMA32(kfb[ks], qf[0][ks], sB0);
      sB1 = MFMA32(kfb[ks], qf[1][ks], sB1);
    }
    __builtin_amdgcn_s_setprio(0);
    // K prefetch for kb+1 (regs consumed; loads land during exp/PV phases)
#pragma unroll
    for (int ks = 0; ks < 4; ++ks) kfa[ks] = *(const bf16x8*)(kp + ks * 16);
#pragma unroll
    for (int ks = 0; ks < 4; ++ks) kfb[ks] = *(const bf16x8*)(kp + 2048 + ks * 16);

    // ---- phase 2: ptrans mt0, PV mt0; ptrans mt1 overlaps in PV shadow ----
    bf16x8 fA00, fA01, fA10, fA11;
    ptrans(sA0, rsum[0], fA00, fA01);
    ptrans(sA1, rsum[1], fA10, fA11);
    __builtin_amdgcn_s_setprio(1);
    o[0][0] = MFMA32(vf[0][0], fA00, o[0][0]);
    o[1][0] = MFMA32(vf[1][0], fA00, o[1][0]);
    o[0][0] = MFMA32(vf[0][1], fA01, o[0][0]);
    o[1][0] = MFMA32(vf[1][1], fA01, o[1][0]);
    o[0][1] = MFMA32(vf[0][0], fA10, o[0][1]);
    o[1][1] = MFMA32(vf[1][0], fA10, o[1][1]);
    o[0][1] = MFMA32(vf[0][1], fA11, o[0][1]);
    o[1][1] = MFMA32(vf[1][1], fA11, o[1][1]);
    __builtin_amdgcn_s_setprio(0);
    // ptrans mt1: independent of PV mt0 -> VALU issues while MFMAs drain
    bf16x8 fB00, fB01, fB10, fB11;
    ptrans(sB0, rsum[0], fB00, fB01);
    ptrans(sB1, rsum[1], fB10, fB11);
    __builtin_amdgcn_s_setprio(1);
    o[0][0] = MFMA32(vf[0][2], fB00, o[0][0]);
    o[1][0] = MFMA32(vf[1][2], fB00, o[1][0]);
    o[0][0] = MFMA32(vf[0][3], fB01, o[0][0]);
    o[1][0] = MFMA32(vf[1][3], fB01, o[1][0]);
    o[0][1] = MFMA32(vf[0][2], fB10, o[0][1]);
    o[1][1] = MFMA32(vf[1][2], fB10, o[1][1]);
    o[0][1] = MFMA32(vf[0][3], fB11, o[0][1]);
    o[1][1] = MFMA32(vf[1][3], fB11, o[1][1]);
    __builtin_amdgcn_s_setprio(0);

    kp += 4096;  // 64 keys * 64 elems
    vp += 64;    // 64 keys
  }

  // normalize + write bf16 chunk partial. O^T: d=dt*32+4*lh+8*g+t, q=qt*32+l31
  unsigned short* cB = chunk ? c1 : c0;
  const int b = bh >> 4, h = bh & 15;
#pragma unroll
  for (int qt = 0; qt < 2; ++qt) {
    float lsum = rsum[qt] + __shfl_xor(rsum[qt], 32);
    float inv = 1.f / lsum;
    int s = q0 + qt * 32 + l31;
#pragma unroll
    for (int dt = 0; dt < 2; ++dt)
#pragma unroll
      for (int g = 0; g < 4; ++g) {
        int d = dt * 32 + 4 * lh + 8 * g;
        size_t idx = ((size_t)(b * 2048 + s)) * 1024 + h * 64 + d;
        ushort4 hv;
#pragma unroll
        for (int t = 0; t < 4; ++t)
          ((unsigned short*)&hv)[t] = f2bf(o[dt][qt][g * 4 + t] * inv);
        *(ushort4*)(cB + idx) = hv;
      }
  }
}

// ---------------- K3b: combine chunk partials: attnB = bf16(c0 + c1) ----------------
__global__ __launch_bounds__(256) void k_comb(const unsigned short* __restrict__ c0,
                                              const unsigned short* __restrict__ c1,
                                              unsigned short* __restrict__ outB,
                                              int n8) {
  int i = blockIdx.x * blockDim.x + threadIdx.x;
  if (i >= n8) return;
  uint4 a = ((const uint4*)c0)[i];
  uint4 b = ((const uint4*)c1)[i];
  uint4 r;
  const unsigned short* pa = (const unsigned short*)&a;
  const unsigned short* pb = (const unsigned short*)&b;
  unsigned short* pr = (unsigned short*)&r;
#pragma unroll
  for (int j = 0; j < 8; ++j) pr[j] = f2bf(bf2f(pa[j]) + bf2f(pb[j]));
  ((uint4*)outB)[i] = r;
}

// ---------------- K4: output projection, plain bf16, fp32 store ----------------
__global__ __launch_bounds__(256, 2) void k_out(const unsigned short* __restrict__ A,
                                                const unsigned short* __restrict__ B,
                                                float* __restrict__ out) {
  __shared__ unsigned short Ah[128 * 32], Bh[128 * 32];
  const int tid = threadIdx.x;
  const int bm = blockIdx.y, n0 = blockIdx.x * 128;
  const int lane = tid & 63, wave = tid >> 6;
  const int wm = (wave & 1) * 64, wn = (wave >> 1) * 64;
  const int l15 = lane & 15, lq = lane >> 4;

  f32x4 acc[4][4];
#pragma unroll
  for (int i = 0; i < 4; i++)
#pragma unroll
    for (int j = 0; j < 4; j++) acc[i][j] = (f32x4){0.f, 0.f, 0.f, 0.f};

  const char* baseA = (const char*)A + (size_t)(bm * 128) * 2048;
  const char* baseB = (const char*)B + (size_t)n0 * 2048;
  const int off0 = tid << 4, row0 = off0 >> 6, seg0 = off0 & 63;
  const int off1 = (tid + 256) << 4, row1 = off1 >> 6, seg1 = off1 & 63;

  for (int k0 = 0; k0 < 1024; k0 += 32) {
    __syncthreads();
    gload_lds16(baseA + (size_t)row0 * 2048 + k0 * 2 + seg0, (char*)Ah + wave * 1024);
    gload_lds16(baseB + (size_t)row0 * 2048 + k0 * 2 + seg0, (char*)Bh + wave * 1024);
    gload_lds16(baseA + (size_t)row1 * 2048 + k0 * 2 + seg1,
                (char*)Ah + 4096 + wave * 1024);
    gload_lds16(baseB + (size_t)row1 * 2048 + k0 * 2 + seg1,
                (char*)Bh + 4096 + wave * 1024);
    __syncthreads();
    bf16x8 ah[4], bh[4];
#pragma unroll
    for (int i = 0; i < 4; ++i) {
      ah[i] = *(const bf16x8*)&Ah[(wm + i * 16 + l15) * 32 + lq * 8];
      bh[i] = *(const bf16x8*)&Bh[(wn + i * 16 + l15) * 32 + lq * 8];
    }
#pragma unroll
    for (int i = 0; i < 4; ++i)
#pragma unroll
      for (int j = 0; j < 4; ++j) acc[i][j] = MFMA16(ah[i], bh[j], acc[i][j]);
  }
#pragma unroll
  for (int i = 0; i < 4; ++i)
#pragma unroll
    for (int j = 0; j < 4; ++j) {
      int colw = n0 + wn + j * 16 + l15;
#pragma unroll
      for (int r = 0; r < 4; ++r) {
        int rowg = bm * 128 + wm + i * 16 + lq * 4 + r;
        out[(size_t)rowg * 1024 + colw] = acc[i][j][r];
      }
    }
}

// ---------------- launch ----------------
extern "C" void kernel_launch(void* const* d_in, const int* in_sizes, int n_in,
                              void* d_out, int out_size, void* d_ws, size_t ws_size,
                              hipStream_t stream) {
  const float* hs = (const float*)d_in[0];
  const float* freqs = (const float*)d_in[1];
  const float* Wq = (const float*)d_in[2];
  const float* Wk = (const float*)d_in[3];
  const float* Wv = (const float*)d_in[4];
  const float* Wo = (const float*)d_in[5];
  float* out = (float*)d_out;

  const size_t MD = (size_t)4096 * 1024;
  const size_t WW = (size_t)1024 * 1024;
  unsigned short* hsH = (unsigned short*)d_ws;   // 8MB; reused as attnB
  unsigned short* WtqH = hsH + MD;
  unsigned short* WtkH = WtqH + WW;
  unsigned short* WtvH = WtkH + WW;
  unsigned short* WtoH = WtvH + WW;
  unsigned short* qB = WtoH + WW;
  unsigned short* kB = qB + MD;
  unsigned short* vB = kB + MD;
  unsigned short* c0 = vB + MD;
  unsigned short* c1 = c0 + MD;
  unsigned short* attnB = hsH;  // hs bf16 dead after k_qkv

  k_split<<<4096, 256, 0, stream>>>(hs, hsH, (int)(MD / 4));
  k_wsplit<<<dim3(32, 32, 4), 256, 0, stream>>>(Wq, Wk, Wv, Wo,
                                                WtqH, WtkH, WtvH, WtoH);
  k_qkv<<<dim3(24, 32), 256, 0, stream>>>(hsH, WtqH, WtkH, WtvH, freqs, qB, kB, vB);
  k_attn<<<512, 256, 0, stream>>>(qB, kB, vB, c0, c1);
  k_comb<<<2048, 256, 0, stream>>>(c0, c1, attnB, (int)(MD / 8));
  k_out<<<dim3(8, 32), 256, 0, stream>>>(attnB, WtoH, out);
}

// Round 7
// 211.722 us; speedup vs baseline: 3.1476x; 1.1011x over previous
//
#include <hip/hip_runtime.h>
#include <hip/hip_bf16.h>
#include <cstdint>

typedef __bf16 bf16x8 __attribute__((ext_vector_type(8)));
typedef float f32x4 __attribute__((ext_vector_type(4)));
typedef float f32x16 __attribute__((ext_vector_type(16)));

#define MFMA16(a, b, c) __builtin_amdgcn_mfma_f32_16x16x32_bf16(a, b, c, 0, 0, 0)
#define MFMA32(a, b, c) __builtin_amdgcn_mfma_f32_32x32x16_bf16(a, b, c, 0, 0, 0)

__device__ __forceinline__ void gload_lds16(const void* g, void* l) {
  __builtin_amdgcn_global_load_lds(
      (const __attribute__((address_space(1))) unsigned int*)g,
      (__attribute__((address_space(3))) unsigned int*)l, 16, 0, 0);
}

__device__ __forceinline__ unsigned short f2bf(float x) {
  union { float f; uint32_t u; } v; v.f = x;
  uint32_t r = v.u + 0x7fff + ((v.u >> 16) & 1);
  return (unsigned short)(r >> 16);
}
__device__ __forceinline__ float bf2f(unsigned short h) {
  union { float f; uint32_t u; } v; v.u = ((uint32_t)h) << 16;
  return v.f;
}
__device__ __forceinline__ f32x16 fzero16() {
  f32x16 v;
#pragma unroll
  for (int i = 0; i < 16; ++i) v[i] = 0.f;
  return v;
}

// S-tile (f32x16, pre-scaled by sc*log2e via Q) -> exp2 -> two PV B-frags.
// ZERO cross-lane ops (V stored with matching key permutation in k_qkv).
__device__ __forceinline__ void ptrans(const f32x16& sv, float& rsum,
                                       bf16x8& f0, bf16x8& f1) {
  float ps[16];
#pragma unroll
  for (int r = 0; r < 16; ++r) ps[r] = __builtin_exp2f(sv[r]);
  float rs = 0.f;
#pragma unroll
  for (int r = 0; r < 16; ++r) rs += ps[r];
  rsum += rs;
  bf16x8 a, b;
#pragma unroll
  for (int r = 0; r < 8; ++r) a[r] = (__bf16)ps[r];
#pragma unroll
  for (int r = 0; r < 8; ++r) b[r] = (__bf16)ps[8 + r];
  f0 = a; f1 = b;
}

// ---------------- K1a: hidden_states -> bf16 ----------------
__global__ __launch_bounds__(256) void k_split(const float* __restrict__ x,
                                               unsigned short* __restrict__ hi, int n4) {
  int i = blockIdx.x * blockDim.x + threadIdx.x;
  if (i >= n4) return;
  float4 v = ((const float4*)x)[i];
  ushort4 h;
  h.x = f2bf(v.x); h.y = f2bf(v.y); h.z = f2bf(v.z); h.w = f2bf(v.w);
  ((ushort4*)hi)[i] = h;
}

// ------------ K1b: transpose weights -> bf16 (fused, z selects W) ------------
__global__ __launch_bounds__(256) void k_wsplit(
    const float* __restrict__ Wq, const float* __restrict__ Wk,
    const float* __restrict__ Wv, const float* __restrict__ Wo,
    unsigned short* __restrict__ WtqH, unsigned short* __restrict__ WtkH,
    unsigned short* __restrict__ WtvH, unsigned short* __restrict__ WtoH) {
  const int z = blockIdx.z;
  const float* W = (z == 0) ? Wq : (z == 1) ? Wk : (z == 2) ? Wv : Wo;
  unsigned short* WtH = (z == 0) ? WtqH : (z == 1) ? WtkH : (z == 2) ? WtvH : WtoH;
  __shared__ float tile[32][33];
  const int bx = blockIdx.x, by = blockIdx.y;
  const int tx = threadIdx.x & 31, ty = threadIdx.x >> 5;
#pragma unroll
  for (int i = 0; i < 4; ++i)
    tile[ty + i * 8][tx] = W[(size_t)(by * 32 + ty + i * 8) * 1024 + bx * 32 + tx];
  __syncthreads();
#pragma unroll
  for (int i = 0; i < 4; ++i) {
    float v = tile[tx][ty + i * 8];
    WtH[(size_t)(bx * 32 + ty + i * 8) * 1024 + by * 32 + tx] = f2bf(v);
  }
}

// ---------------- K2: QKV GEMM, plain bf16, global_load_lds staging ----------------
// K and V are stored FRAG-LINEAR: 1KB blocks in the exact order k_attn's waves
// read them (kb-block, half/dt, ks), element (lane*8+e) inside -- so every
// per-kb load in k_attn is a fully coalesced dwordx4 (16 lines vs 32-line
// scatter of the row-major layout).
//   K: off(s,d) = (s>>10)*65536 + ((s>>6)&15)*4096 + ((s>>5)&1)*2048
//                + (d>>4)*512 + ((s&31) + 32*((d>>3)&1))*8 + (d&7)
//   V: off(sp,d) = (sp>>10)*65536 + ((sp>>6)&15)*4096 + (d>>5)*2048
//                + ((sp>>4)&3)*512 + ((d&31) + 32*((sp>>3)&1))*8 + (sp&7)
// (sp = key s permuted within 16-groups to match S-register order.)
__global__ __launch_bounds__(256, 2) void k_qkv(
    const unsigned short* __restrict__ hsH,
    const unsigned short* __restrict__ WqH, const unsigned short* __restrict__ WkH,
    const unsigned short* __restrict__ WvH, const float* __restrict__ freqs,
    unsigned short* __restrict__ qB, unsigned short* __restrict__ kB,
    unsigned short* __restrict__ vB) {
  __shared__ unsigned short Ah[128 * 32], Bh[128 * 32];  // 8KB each, 64B rows
  const int tid = threadIdx.x;
  const int bm = blockIdx.y, bn = blockIdx.x;
  const int w = bn >> 3;           // 0=q 1=k 2=v
  const int n0 = (bn & 7) * 128;
  const unsigned short* WH = (w == 0) ? WqH : (w == 1) ? WkH : WvH;
  const int lane = tid & 63, wave = tid >> 6;
  const int wm = (wave & 1) * 64, wn = (wave >> 1) * 64;
  const int l15 = lane & 15, lq = lane >> 4;

  f32x4 acc[4][4];
#pragma unroll
  for (int i = 0; i < 4; i++)
#pragma unroll
    for (int j = 0; j < 4; j++) acc[i][j] = (f32x4){0.f, 0.f, 0.f, 0.f};

  const char* baseA = (const char*)hsH + (size_t)(bm * 128) * 2048;
  const char* baseB = (const char*)WH + (size_t)n0 * 2048;
  const int off0 = tid << 4, row0 = off0 >> 6, seg0 = off0 & 63;
  const int off1 = (tid + 256) << 4, row1 = off1 >> 6, seg1 = off1 & 63;

  for (int k0 = 0; k0 < 1024; k0 += 32) {
    __syncthreads();
    gload_lds16(baseA + (size_t)row0 * 2048 + k0 * 2 + seg0, (char*)Ah + wave * 1024);
    gload_lds16(baseB + (size_t)row0 * 2048 + k0 * 2 + seg0, (char*)Bh + wave * 1024);
    gload_lds16(baseA + (size_t)row1 * 2048 + k0 * 2 + seg1,
                (char*)Ah + 4096 + wave * 1024);
    gload_lds16(baseB + (size_t)row1 * 2048 + k0 * 2 + seg1,
                (char*)Bh + 4096 + wave * 1024);
    __syncthreads();
    bf16x8 ah[4], bh[4];
#pragma unroll
    for (int i = 0; i < 4; ++i) {
      ah[i] = *(const bf16x8*)&Ah[(wm + i * 16 + l15) * 32 + lq * 8];
      bh[i] = *(const bf16x8*)&Bh[(wn + i * 16 + l15) * 32 + lq * 8];
    }
#pragma unroll
    for (int i = 0; i < 4; ++i)
#pragma unroll
      for (int j = 0; j < 4; ++j) acc[i][j] = MFMA16(ah[i], bh[j], acc[i][j]);
  }

  // epilogue: C/D layout col=lane&15, row=(lane>>4)*4+r. RoPE for q,k.
  // Softmax scale * log2(e) folded into Q (f32, commutes with RoPE rotation).
  unsigned short* dst = (w == 0) ? qB : (w == 1) ? kB : vB;
#pragma unroll
  for (int i = 0; i < 4; ++i) {
#pragma unroll
    for (int j = 0; j < 4; ++j) {
      int colw = n0 + wn + j * 16 + l15;
      int h = colw >> 6, d = colw & 63;
#pragma unroll
      for (int r = 0; r < 4; ++r) {
        int rowg = bm * 128 + wm + i * 16 + lq * 4 + r;
        int s = rowg & 2047, b = rowg >> 11;
        float val = acc[i][j][r];
        size_t bhb = (size_t)(b * 16 + h) * 131072;
        if (w < 2) {
          float partner = __shfl_xor(val, 1);
          int jj = d >> 1;
          float cs = freqs[(s * 32 + jj) * 2 + 0];
          float sn = freqs[(s * 32 + jj) * 2 + 1];
          float res = (d & 1) ? (partner * sn + val * cs) : (val * cs - partner * sn);
          if (w == 0) {
            res *= 0.18033688011112042f;  // 0.125 * log2(e)
            dst[(((size_t)(b * 16 + h)) * 2048 + s) * 64 + d] = f2bf(res);
          } else {
            size_t off = (size_t)(s >> 10) * 65536 + ((s >> 6) & 15) * 4096 +
                         ((s >> 5) & 1) * 2048 + (d >> 4) * 512 +
                         ((s & 31) + 32 * ((d >> 3) & 1)) * 8 + (d & 7);
            dst[bhb + off] = f2bf(res);
          }
        } else {
          // key permutation within 16-groups (swap middle 4-blocks)
          int sp = (s & ~12) | ((s & 4) << 1) | ((s & 8) >> 1);
          size_t off = (size_t)(sp >> 10) * 65536 + ((sp >> 6) & 15) * 4096 +
                       (d >> 5) * 2048 + ((sp >> 4) & 3) * 512 +
                       ((d & 31) + 32 * ((sp >> 3) & 1)) * 8 + (sp & 7);
          dst[bhb + off] = f2bf(val);
        }
      }
    }
  }
}

// ------- K3: chunked attention, ILP reorder + frag-linear coalesced K/V -------
// Grid 512; id = xcd + 8*(x + 8*hi), group g=(bh,chunk)=xcd+8*hi so all 8
// q-tile blocks of a (bh,chunk) share ids mod 8 -> same XCD -> K/V L2 reuse.
// K/V loads are now 1KB fully-coalesced dwordx4 per frag (was 32-line scatter).
__global__ __launch_bounds__(256, 2) void k_attn(
    const unsigned short* __restrict__ qB, const unsigned short* __restrict__ kB,
    const unsigned short* __restrict__ vB,
    unsigned short* __restrict__ c0, unsigned short* __restrict__ c1) {
  const int tid = threadIdx.x, lane = tid & 63, wave = tid >> 6;
  const int l31 = lane & 31, lh = lane >> 5;
  const int bid = blockIdx.x;
  const int x = (bid >> 3) & 7;
  const int gg = (bid & 7) + 8 * (bid >> 6);
  const int bh = gg & 31;
  const int chunk = gg >> 5;
  const int q0 = x * 256 + wave * 64;
  const size_t base = (size_t)bh * 131072;

  // Q B-frags (pre-scaled in k_qkv): lane n=l31 -> query q0+qt*32+l31, k=ks*16+lh*8
  bf16x8 qf[2][4];
#pragma unroll
  for (int qt = 0; qt < 2; ++qt)
#pragma unroll
    for (int ks = 0; ks < 4; ++ks)
      qf[qt][ks] = *(const bf16x8*)(qB + base + (size_t)(q0 + qt * 32 + l31) * 64 +
                                    ks * 16 + lh * 8);

  // frag-linear: kfa at kp+ks*512, kfb at kp+2048+ks*512; vf at vp+dt*2048+ks*512
  const unsigned short* kp = kB + base + chunk * 65536 + lane * 8;
  const unsigned short* vp = vB + base + chunk * 65536 + lane * 8;

  // preload K for kb=0 (both 32-key halves)
  bf16x8 kfa[4], kfb[4];
#pragma unroll
  for (int ks = 0; ks < 4; ++ks) {
    kfa[ks] = *(const bf16x8*)(kp + ks * 512);
    kfb[ks] = *(const bf16x8*)(kp + 2048 + ks * 512);
  }
  kp += 4096;

  f32x16 o[2][2];  // [dt][qt]
#pragma unroll
  for (int a = 0; a < 2; ++a)
#pragma unroll
    for (int bq = 0; bq < 2; ++bq) o[a][bq] = fzero16();
  float rsum[2] = {0.f, 0.f};

  for (int kb = 0; kb < 16; ++kb) {
    // V^T frags up-front (consumed at iter end -> full S/exp phase to land)
    bf16x8 vf[2][4];
#pragma unroll
    for (int dt = 0; dt < 2; ++dt)
#pragma unroll
      for (int ks = 0; ks < 4; ++ks)
        vf[dt][ks] = *(const bf16x8*)(vp + dt * 2048 + ks * 512);

    // ---- phase 1: all 16 S-MFMAs (both mt halves, both qt tiles) ----
    f32x16 sA0 = fzero16(), sA1 = fzero16();  // mt0
    f32x16 sB0 = fzero16(), sB1 = fzero16();  // mt1
    __builtin_amdgcn_s_setprio(1);
#pragma unroll
    for (int ks = 0; ks < 4; ++ks) {
      sA0 = MFMA32(kfa[ks], qf[0][ks], sA0);
      sA1 = MFMA32(kfa[ks], qf[1][ks], sA1);
    }
#pragma unroll
    for (int ks = 0; ks < 4; ++ks) {
      sB0 = MFMA32(kfb[ks], qf[0][ks], sB0);
      sB1 = MFMA32(kfb[ks], qf[1][ks], sB1);
    }
    __builtin_amdgcn_s_setprio(0);
    // K prefetch for kb+1 (regs consumed; loads land during exp/PV phases)
#pragma unroll
    for (int ks = 0; ks < 4; ++ks) kfa[ks] = *(const bf16x8*)(kp + ks * 512);
#pragma unroll
    for (int ks = 0; ks < 4; ++ks)
      kfb[ks] = *(const bf16x8*)(kp + 2048 + ks * 512);

    // ---- phase 2: ptrans mt0, PV mt0; ptrans mt1 overlaps in PV shadow ----
    bf16x8 fA00, fA01, fA10, fA11;
    ptrans(sA0, rsum[0], fA00, fA01);
    ptrans(sA1, rsum[1], fA10, fA11);
    __builtin_amdgcn_s_setprio(1);
    o[0][0] = MFMA32(vf[0][0], fA00, o[0][0]);
    o[1][0] = MFMA32(vf[1][0], fA00, o[1][0]);
    o[0][0] = MFMA32(vf[0][1], fA01, o[0][0]);
    o[1][0] = MFMA32(vf[1][1], fA01, o[1][0]);
    o[0][1] = MFMA32(vf[0][0], fA10, o[0][1]);
    o[1][1] = MFMA32(vf[1][0], fA10, o[1][1]);
    o[0][1] = MFMA32(vf[0][1], fA11, o[0][1]);
    o[1][1] = MFMA32(vf[1][1], fA11, o[1][1]);
    __builtin_amdgcn_s_setprio(0);
    // ptrans mt1: independent of PV mt0 -> VALU issues while MFMAs drain
    bf16x8 fB00, fB01, fB10, fB11;
    ptrans(sB0, rsum[0], fB00, fB01);
    ptrans(sB1, rsum[1], fB10, fB11);
    __builtin_amdgcn_s_setprio(1);
    o[0][0] = MFMA32(vf[0][2], fB00, o[0][0]);
    o[1][0] = MFMA32(vf[1][2], fB00, o[1][0]);
    o[0][0] = MFMA32(vf[0][3], fB01, o[0][0]);
    o[1][0] = MFMA32(vf[1][3], fB01, o[1][0]);
    o[0][1] = MFMA32(vf[0][2], fB10, o[0][1]);
    o[1][1] = MFMA32(vf[1][2], fB10, o[1][1]);
    o[0][1] = MFMA32(vf[0][3], fB11, o[0][1]);
    o[1][1] = MFMA32(vf[1][3], fB11, o[1][1]);
    __builtin_amdgcn_s_setprio(0);

    kp += 4096;  // next 64-key block
    vp += 4096;
  }

  // normalize + write bf16 chunk partial. O^T: d=dt*32+4*lh+8*g+t, q=qt*32+l31
  unsigned short* cB = chunk ? c1 : c0;
  const int b = bh >> 4, h = bh & 15;
#pragma unroll
  for (int qt = 0; qt < 2; ++qt) {
    float lsum = rsum[qt] + __shfl_xor(rsum[qt], 32);
    float inv = 1.f / lsum;
    int s = q0 + qt * 32 + l31;
#pragma unroll
    for (int dt = 0; dt < 2; ++dt)
#pragma unroll
      for (int g = 0; g < 4; ++g) {
        int d = dt * 32 + 4 * lh + 8 * g;
        size_t idx = ((size_t)(b * 2048 + s)) * 1024 + h * 64 + d;
        ushort4 hv;
#pragma unroll
        for (int t = 0; t < 4; ++t)
          ((unsigned short*)&hv)[t] = f2bf(o[dt][qt][g * 4 + t] * inv);
        *(ushort4*)(cB + idx) = hv;
      }
  }
}

// ---------------- K3b: combine chunk partials: attnB = bf16(c0 + c1) ----------------
__global__ __launch_bounds__(256) void k_comb(const unsigned short* __restrict__ c0,
                                              const unsigned short* __restrict__ c1,
                                              unsigned short* __restrict__ outB,
                                              int n8) {
  int i = blockIdx.x * blockDim.x + threadIdx.x;
  if (i >= n8) return;
  uint4 a = ((const uint4*)c0)[i];
  uint4 b = ((const uint4*)c1)[i];
  uint4 r;
  const unsigned short* pa = (const unsigned short*)&a;
  const unsigned short* pb = (const unsigned short*)&b;
  unsigned short* pr = (unsigned short*)&r;
#pragma unroll
  for (int j = 0; j < 8; ++j) pr[j] = f2bf(bf2f(pa[j]) + bf2f(pb[j]));
  ((uint4*)outB)[i] = r;
}

// ---------------- K4: output projection, plain bf16, fp32 store ----------------
__global__ __launch_bounds__(256, 2) void k_out(const unsigned short* __restrict__ A,
                                                const unsigned short* __restrict__ B,
                                                float* __restrict__ out) {
  __shared__ unsigned short Ah[128 * 32], Bh[128 * 32];
  const int tid = threadIdx.x;
  const int bm = blockIdx.y, n0 = blockIdx.x * 128;
  const int lane = tid & 63, wave = tid >> 6;
  const int wm = (wave & 1) * 64, wn = (wave >> 1) * 64;
  const int l15 = lane & 15, lq = lane >> 4;

  f32x4 acc[4][4];
#pragma unroll
  for (int i = 0; i < 4; i++)
#pragma unroll
    for (int j = 0; j < 4; j++) acc[i][j] = (f32x4){0.f, 0.f, 0.f, 0.f};

  const char* baseA = (const char*)A + (size_t)(bm * 128) * 2048;
  const char* baseB = (const char*)B + (size_t)n0 * 2048;
  const int off0 = tid << 4, row0 = off0 >> 6, seg0 = off0 & 63;
  const int off1 = (tid + 256) << 4, row1 = off1 >> 6, seg1 = off1 & 63;

  for (int k0 = 0; k0 < 1024; k0 += 32) {
    __syncthreads();
    gload_lds16(baseA + (size_t)row0 * 2048 + k0 * 2 + seg0, (char*)Ah + wave * 1024);
    gload_lds16(baseB + (size_t)row0 * 2048 + k0 * 2 + seg0, (char*)Bh + wave * 1024);
    gload_lds16(baseA + (size_t)row1 * 2048 + k0 * 2 + seg1,
                (char*)Ah + 4096 + wave * 1024);
    gload_lds16(baseB + (size_t)row1 * 2048 + k0 * 2 + seg1,
                (char*)Bh + 4096 + wave * 1024);
    __syncthreads();
    bf16x8 ah[4], bh[4];
#pragma unroll
    for (int i = 0; i < 4; ++i) {
      ah[i] = *(const bf16x8*)&Ah[(wm + i * 16 + l15) * 32 + lq * 8];
      bh[i] = *(const bf16x8*)&Bh[(wn + i * 16 + l15) * 32 + lq * 8];
    }
#pragma unroll
    for (int i = 0; i < 4; ++i)
#pragma unroll
      for (int j = 0; j < 4; ++j) acc[i][j] = MFMA16(ah[i], bh[j], acc[i][j]);
  }
#pragma unroll
  for (int i = 0; i < 4; ++i)
#pragma unroll
    for (int j = 0; j < 4; ++j) {
      int colw = n0 + wn + j * 16 + l15;
#pragma unroll
      for (int r = 0; r < 4; ++r) {
        int rowg = bm * 128 + wm + i * 16 + lq * 4 + r;
        out[(size_t)rowg * 1024 + colw] = acc[i][j][r];
      }
    }
}

// ---------------- launch ----------------
extern "C" void kernel_launch(void* const* d_in, const int* in_sizes, int n_in,
                              void* d_out, int out_size, void* d_ws, size_t ws_size,
                              hipStream_t stream) {
  const float* hs = (const float*)d_in[0];
  const float* freqs = (const float*)d_in[1];
  const float* Wq = (const float*)d_in[2];
  const float* Wk = (const float*)d_in[3];
  const float* Wv = (const float*)d_in[4];
  const float* Wo = (const float*)d_in[5];
  float* out = (float*)d_out;

  const size_t MD = (size_t)4096 * 1024;
  const size_t WW = (size_t)1024 * 1024;
  unsigned short* hsH = (unsigned short*)d_ws;   // 8MB; reused as attnB
  unsigned short* WtqH = hsH + MD;
  unsigned short* WtkH = WtqH + WW;
  unsigned short* WtvH = WtkH + WW;
  unsigned short* WtoH = WtvH + WW;
  unsigned short* qB = WtoH + WW;
  unsigned short* kB = qB + MD;
  unsigned short* vB = kB + MD;
  unsigned short* c0 = vB + MD;
  unsigned short* c1 = c0 + MD;
  unsigned short* attnB = hsH;  // hs bf16 dead after k_qkv

  k_split<<<4096, 256, 0, stream>>>(hs, hsH, (int)(MD / 4));
  k_wsplit<<<dim3(32, 32, 4), 256, 0, stream>>>(Wq, Wk, Wv, Wo,
                                                WtqH, WtkH, WtvH, WtoH);
  k_qkv<<<dim3(24, 32), 256, 0, stream>>>(hsH, WtqH, WtkH, WtvH, freqs, qB, kB, vB);
  k_attn<<<512, 256, 0, stream>>>(qB, kB, vB, c0, c1);
  k_comb<<<2048, 256, 0, stream>>>(c0, c1, attnB, (int)(MD / 8));
  k_out<<<dim3(8, 32), 256, 0, stream>>>(attnB, WtoH, out);
}